// Round 1
// baseline (524.861 us; speedup 1.0000x reference)
//
#include <hip/hip_runtime.h>
#include <hip/hip_bf16.h>

#define NS 32
#define NE 32
#define BB 64
#define DD 1024
#define HH 16
#define SB (NS * BB)  // 2048

typedef __attribute__((ext_vector_type(4))) float f32x4;
typedef __attribute__((ext_vector_type(8))) short short8;

static __device__ __forceinline__ unsigned short f2bf(float f) {
  union { float f; unsigned int u; } c{f};
  unsigned int u = c.u;
  return (unsigned short)((u + 0x7FFFu + ((u >> 16) & 1u)) >> 16);  // RNE
}

// ---------- k0a: q = (Wq @ query + bq) * 1/sqrt(hd) ----------
extern "C" __global__ void k0a_q(const float* __restrict__ w,
                                 const float* __restrict__ bq,
                                 const float* __restrict__ query,
                                 float* __restrict__ qv) {
  int wid = (blockIdx.x * blockDim.x + threadIdx.x) >> 6;  // 0..1023 = output row
  int lane = threadIdx.x & 63;
  const float* row = w + (size_t)wid * DD;
  float sum = 0.f;
  for (int k = lane; k < DD; k += 64) sum += row[k] * query[k];
  #pragma unroll
  for (int off = 32; off; off >>= 1) sum += __shfl_xor(sum, off);
  if (lane == 0) qv[wid] = (sum + bq[wid]) * 0.125f;  // scale = 1/8
}

// ---------- k0b: rT[h][d] = sum_j q[h*64+j] * Wk[h*64+j][d]  (bf16) ----------
extern "C" __global__ void k0b_r(const float* __restrict__ w,
                                 const float* __restrict__ qv,
                                 unsigned short* __restrict__ rT) {
  int gt = blockIdx.x * blockDim.x + threadIdx.x;  // 0..16383
  int h = gt >> 10, d = gt & 1023;
  const float* wk = w + (size_t)DD * DD;
  float sum = 0.f;
  #pragma unroll 8
  for (int j = 0; j < 64; ++j)
    sum += qv[h * 64 + j] * wk[(size_t)(h * 64 + j) * DD + d];
  rT[gt] = f2bf(sum);
}

// ---------- k0c: bf16 copies of Wv and W_out ----------
extern "C" __global__ void k0c_conv(const float* __restrict__ wv_f,
                                    const float* __restrict__ wo_f,
                                    unsigned short* __restrict__ wv,
                                    unsigned short* __restrict__ wo) {
  int i = blockIdx.x * blockDim.x + threadIdx.x;  // float4 index, 0..524287
  if (i < 262144) {
    float4 v = reinterpret_cast<const float4*>(wv_f)[i];
    ushort4 p{f2bf(v.x), f2bf(v.y), f2bf(v.z), f2bf(v.w)};
    reinterpret_cast<ushort4*>(wv)[i] = p;
  } else {
    int j = i - 262144;
    float4 v = reinterpret_cast<const float4*>(wo_f)[j];
    ushort4 p{f2bf(v.x), f2bf(v.y), f2bf(v.z), f2bf(v.w)};
    reinterpret_cast<ushort4*>(wo)[j] = p;
  }
}

// ---------- k1: per-(s,b): scores -> softmax -> agg[sb][h][d] (bf16) ----------
extern "C" __global__ __launch_bounds__(512, 4)
void k1_scores_agg(const float* __restrict__ ent,
                   const unsigned char* __restrict__ mask,
                   const unsigned short* __restrict__ rT,
                   unsigned short* __restrict__ agg,
                   unsigned char* __restrict__ flags) {
  __shared__ unsigned short elds[NE * DD];        // 64 KB, XOR-swizzled
  __shared__ float slds[NE][HH];                  // scores
  __shared__ unsigned short attnT[HH][NE];        // bf16 attn, [h][e]
  __shared__ unsigned char mlds[NE];

  const int sb = blockIdx.x;
  const int s = sb >> 6, b = sb & 63;
  const int t = threadIdx.x;
  const int lane = t & 63;
  const int wave = t >> 6;

  // stage entities: fp32 global -> bf16 LDS (swizzle byte^((e&7)<<4) == elem^((e&7)<<3))
  const float* base = ent + ((size_t)(s * NE) * BB + b) * DD;
  #pragma unroll 4
  for (int i = 0; i < 16; ++i) {
    int f4 = t + 512 * i;          // 0..8191
    int e = f4 >> 8;
    int d0 = (f4 & 255) << 2;
    float4 v = *reinterpret_cast<const float4*>(base + (size_t)e * (BB * DD) + d0);
    int sidx = ((e << 10) + d0) ^ ((e & 7) << 3);
    ushort4 pk{f2bf(v.x), f2bf(v.y), f2bf(v.z), f2bf(v.w)};
    *reinterpret_cast<ushort4*>(&elds[sidx]) = pk;
  }
  if (t < NE) mlds[t] = mask[(size_t)(s * NE + t) * BB + b];
  __syncthreads();

  // scores: waves 0,1 -> scores[e][h], e-tile = wave. A=ent(LDS), B=rT(L2). K=1024.
  if (wave < 2) {
    const int g = lane >> 4, m = lane & 15;
    const int e = wave * 16 + m;
    f32x4 acc = {0.f, 0.f, 0.f, 0.f};
    #pragma unroll 4
    for (int ks = 0; ks < 32; ++ks) {
      int d0 = (ks << 5) + (g << 3);
      short8 a = *reinterpret_cast<const short8*>(&elds[((e << 10) + d0) ^ ((e & 7) << 3)]);
      short8 bb = *reinterpret_cast<const short8*>(rT + (m << 10) + d0);
      acc = __builtin_amdgcn_mfma_f32_16x16x32_bf16(a, bb, acc, 0, 0, 0);
    }
    #pragma unroll
    for (int r = 0; r < 4; ++r)
      slds[wave * 16 + (g << 2) + r][m] = acc[r];
  }
  __syncthreads();

  // softmax over e per (h): half-wave owns one h (32 lanes = 32 e's)
  {
    const int h = t >> 5, e = t & 31;
    bool msk = mlds[e] != 0;
    float v = msk ? -3.4e38f : slds[e][h];
    float mx = v;
    #pragma unroll
    for (int off = 16; off; off >>= 1) mx = fmaxf(mx, __shfl_xor(mx, off));
    float ex = msk ? 0.f : __expf(v - mx);
    float sm = ex;
    #pragma unroll
    for (int off = 16; off; off >>= 1) sm += __shfl_xor(sm, off);
    float at = sm > 0.f ? ex / sm : 0.f;
    attnT[h][e] = f2bf(at);
  }
  if (t == 0) {
    unsigned char all = 1;
    for (int e = 0; e < NE; ++e) all &= (mlds[e] ? (unsigned char)1 : (unsigned char)0);
    flags[sb] = all;
  }
  __syncthreads();

  // agg[h][d] = sum_e attn[h][e]*ent[e][d]: one K=32 MFMA per 16-d tile; 8 tiles/wave
  {
    const int g = lane >> 4, c = lane & 15;
    short8 a = *reinterpret_cast<const short8*>(&attnT[c][g << 3]);  // A[m=h=c][k=8g+j]
    unsigned short* ob = agg + ((size_t)sb << 14);
    #pragma unroll
    for (int q = 0; q < 8; ++q) {
      const int nt = (wave << 3) + q;
      const int d = (nt << 4) + c;
      short8 bb;
      #pragma unroll
      for (int j = 0; j < 8; ++j) {
        int e = (g << 3) + j;  // same k-order as A
        bb[j] = (short)elds[((e << 10) + d) ^ ((e & 7) << 3)];
      }
      f32x4 acc = {0.f, 0.f, 0.f, 0.f};
      acc = __builtin_amdgcn_mfma_f32_16x16x32_bf16(a, bb, acc, 0, 0, 0);
      #pragma unroll
      for (int r = 0; r < 4; ++r)
        ob[(((g << 2) + r) << 10) + d] = f2bf(acc[r]);  // agg[h=4g+r][d]
    }
  }
}

// ---------- k2: ctx[sb][h*64+d'] = agg[sb][h][:] @ Wv_h^T + bv ----------
extern "C" __global__ __launch_bounds__(256, 4)
void k2_ctx(const unsigned short* __restrict__ agg,
            const unsigned short* __restrict__ wv,
            const float* __restrict__ bv,
            unsigned short* __restrict__ ctx) {
  const int mt = blockIdx.x;   // sb tile of 64
  const int h = blockIdx.y;    // head
  const int t = threadIdx.x, lane = t & 63, wave = t >> 6;
  const int g = lane >> 4, c = lane & 15;
  const int row0 = mt * 64 + wave * 16;
  f32x4 acc[4] = {{0,0,0,0},{0,0,0,0},{0,0,0,0},{0,0,0,0}};
  #pragma unroll 2
  for (int ks = 0; ks < 32; ++ks) {
    int k0 = (ks << 5) + (g << 3);
    short8 a = *reinterpret_cast<const short8*>(agg + ((size_t)((row0 + c) * 16 + h) << 10) + k0);
    #pragma unroll
    for (int nt = 0; nt < 4; ++nt) {
      short8 bb = *reinterpret_cast<const short8*>(wv + ((size_t)(h * 64 + nt * 16 + c) << 10) + k0);
      acc[nt] = __builtin_amdgcn_mfma_f32_16x16x32_bf16(a, bb, acc[nt], 0, 0, 0);
    }
  }
  #pragma unroll
  for (int nt = 0; nt < 4; ++nt)
    #pragma unroll
    for (int r = 0; r < 4; ++r) {
      int col = h * 64 + nt * 16 + c;
      ctx[((size_t)(row0 + (g << 2) + r) << 10) + col] = f2bf(acc[nt][r] + bv[col]);
    }
}

// ---------- k3: out[sb][n] = ctx[sb][:] @ W_out^T + b_out (fp32), masked rows -> 0 ----------
extern "C" __global__ __launch_bounds__(256, 4)
void k3_out(const unsigned short* __restrict__ ctx,
            const unsigned short* __restrict__ wo,
            const float* __restrict__ bias,
            const unsigned char* __restrict__ flags,
            float* __restrict__ out) {
  const int mt = blockIdx.x;
  const int n0 = blockIdx.y * 64;
  const int t = threadIdx.x, lane = t & 63, wave = t >> 6;
  const int g = lane >> 4, c = lane & 15;
  const int row0 = mt * 64 + wave * 16;
  f32x4 acc[4] = {{0,0,0,0},{0,0,0,0},{0,0,0,0},{0,0,0,0}};
  #pragma unroll 2
  for (int ks = 0; ks < 32; ++ks) {
    int k0 = (ks << 5) + (g << 3);
    short8 a = *reinterpret_cast<const short8*>(ctx + ((size_t)(row0 + c) << 10) + k0);
    #pragma unroll
    for (int nt = 0; nt < 4; ++nt) {
      short8 bb = *reinterpret_cast<const short8*>(wo + ((size_t)(n0 + nt * 16 + c) << 10) + k0);
      acc[nt] = __builtin_amdgcn_mfma_f32_16x16x32_bf16(a, bb, acc[nt], 0, 0, 0);
    }
  }
  #pragma unroll
  for (int nt = 0; nt < 4; ++nt)
    #pragma unroll
    for (int r = 0; r < 4; ++r) {
      int row = row0 + (g << 2) + r;
      int col = n0 + nt * 16 + c;
      float v = acc[nt][r] + bias[col];
      if (flags[row]) v = 0.f;
      out[(size_t)row * DD + col] = v;
    }
}

extern "C" void kernel_launch(void* const* d_in, const int* in_sizes, int n_in,
                              void* d_out, int out_size, void* d_ws, size_t ws_size,
                              hipStream_t stream) {
  const float* ent = (const float*)d_in[0];
  const unsigned char* mask = (const unsigned char*)d_in[1];
  const float* query = (const float*)d_in[3];
  const float* ipw = (const float*)d_in[4];
  const float* ipb = (const float*)d_in[5];
  const float* opw = (const float*)d_in[6];
  const float* opb = (const float*)d_in[7];
  float* out = (float*)d_out;

  char* ws = (char*)d_ws;
  float* qv = (float*)(ws + 0);                       // 4 KB
  unsigned char* flags = (unsigned char*)(ws + 4096); // 2 KB
  unsigned short* rT = (unsigned short*)(ws + 8192);  // 32 KB
  unsigned short* wv = (unsigned short*)(ws + 65536);                 // 2 MB
  unsigned short* wo = (unsigned short*)(ws + 65536 + (2u << 20));    // 2 MB
  unsigned short* ctx = (unsigned short*)(ws + 65536 + (4u << 20));   // 4 MB
  unsigned short* agg = (unsigned short*)(ws + 65536 + (8u << 20));   // 64 MB

  hipLaunchKernelGGL(k0a_q, dim3(256), dim3(256), 0, stream, ipw, ipb, query, qv);
  hipLaunchKernelGGL(k0b_r, dim3(64), dim3(256), 0, stream, ipw, qv, rT);
  hipLaunchKernelGGL(k0c_conv, dim3(2048), dim3(256), 0, stream,
                     ipw + (size_t)2 * DD * DD, opw, wv, wo);
  hipLaunchKernelGGL(k1_scores_agg, dim3(SB), dim3(512), 0, stream,
                     ent, mask, rT, agg, flags);
  hipLaunchKernelGGL(k2_ctx, dim3(32, 16), dim3(256), 0, stream,
                     agg, wv, ipb + 2 * DD, ctx);
  hipLaunchKernelGGL(k3_out, dim3(32, 16), dim3(256), 0, stream,
                     ctx, wo, opb, flags, out);
}